// Round 1
// baseline (1677.405 us; speedup 1.0000x reference)
//
#include <hip/hip_runtime.h>
#include <math.h>

#define TT 2048   // tokens
#define NP 2048   // num params (N)
#define BB 8      // batch
#define DD 512    // d_model = kdim = vdim

#define LOG_A (-7.6246189861593985f)  // -log(2048)

// ---------------------------------------------------------------------------
// Generic NN GEMM: C[M,N] = A[M,K] @ B[K,N], all fp32 row-major.
// 128x128 tile, BK=16, 256 threads, 8x8 micro-tile.
// ---------------------------------------------------------------------------
__global__ __launch_bounds__(256) void gemm_nn(
    const float* __restrict__ A, const float* __restrict__ B,
    float* __restrict__ C, int M, int N, int K)
{
    __shared__ float As[16][132];
    __shared__ float Bs[16][132];
    const int tid = threadIdx.x;
    const int tx = tid & 15;
    const int ty = tid >> 4;
    const int row0 = blockIdx.y * 128;
    const int col0 = blockIdx.x * 128;
    float acc[8][8] = {};

    for (int k0 = 0; k0 < K; k0 += 16) {
        #pragma unroll
        for (int i = tid; i < 512; i += 256) {
            int r = i >> 2;
            int c = (i & 3) << 2;
            float4 av = *reinterpret_cast<const float4*>(
                &A[(size_t)(row0 + r) * K + k0 + c]);
            As[c + 0][r] = av.x; As[c + 1][r] = av.y;
            As[c + 2][r] = av.z; As[c + 3][r] = av.w;
        }
        #pragma unroll
        for (int i = tid; i < 512; i += 256) {
            int r = i >> 5;
            int c = (i & 31) << 2;
            *reinterpret_cast<float4*>(&Bs[r][c]) =
                *reinterpret_cast<const float4*>(&B[(size_t)(k0 + r) * N + col0 + c]);
        }
        __syncthreads();
        #pragma unroll
        for (int kk = 0; kk < 16; ++kk) {
            float a[8], bf[8];
            #pragma unroll
            for (int i = 0; i < 8; ++i) a[i] = As[kk][ty * 8 + i];
            #pragma unroll
            for (int j = 0; j < 8; ++j) bf[j] = Bs[kk][tx * 8 + j];
            #pragma unroll
            for (int i = 0; i < 8; ++i)
                #pragma unroll
                for (int j = 0; j < 8; ++j)
                    acc[i][j] = fmaf(a[i], bf[j], acc[i][j]);
        }
        __syncthreads();
    }
    #pragma unroll
    for (int i = 0; i < 8; ++i) {
        float* crow = &C[(size_t)(row0 + ty * 8 + i) * N + col0 + tx * 8];
        *reinterpret_cast<float4*>(crow) =
            make_float4(acc[i][0], acc[i][1], acc[i][2], acc[i][3]);
        *reinterpret_cast<float4*>(crow + 4) =
            make_float4(acc[i][4], acc[i][5], acc[i][6], acc[i][7]);
    }
}

// ---------------------------------------------------------------------------
// Row squared-norm: out[r] = sum_d X[r][d]^2. One wave (64 lanes) per row.
// ---------------------------------------------------------------------------
__global__ __launch_bounds__(256) void rownorm(
    const float* __restrict__ X, float* __restrict__ o, int rows)
{
    int w = blockIdx.x * 4 + (threadIdx.x >> 6);
    int lane = threadIdx.x & 63;
    if (w >= rows) return;
    const float* xr = X + (size_t)w * DD;
    float s = 0.f;
    #pragma unroll
    for (int i = lane; i < DD; i += 64) { float x = xr[i]; s = fmaf(x, x, s); }
    #pragma unroll
    for (int off = 32; off; off >>= 1) s += __shfl_down(s, off, 64);
    if (lane == 0) o[w] = s;
}

// ---------------------------------------------------------------------------
// NT GEMM + cost epilogue:
//   S[t,n] = dot(QP[t,:], KP[b,n,:])
//   Kmat[b,t,n] = -sqrt(max(q2[t] + k2[b,n] - 2 S, 0))
// ---------------------------------------------------------------------------
__global__ __launch_bounds__(256) void gemm_nt_cost(
    const float* __restrict__ QP, const float* __restrict__ KP,
    const float* __restrict__ q2, const float* __restrict__ k2,
    float* __restrict__ Kmat)
{
    const int b = blockIdx.z;
    const float* Bb  = KP + (size_t)b * NP * DD;
    const float* k2b = k2 + (size_t)b * NP;
    float* Kb = Kmat + (size_t)b * TT * NP;

    __shared__ float As[16][132];
    __shared__ float Bs[16][132];
    const int tid = threadIdx.x;
    const int tx = tid & 15;
    const int ty = tid >> 4;
    const int row0 = blockIdx.y * 128;   // t tile
    const int col0 = blockIdx.x * 128;   // n tile
    float acc[8][8] = {};

    for (int k0 = 0; k0 < DD; k0 += 16) {
        #pragma unroll
        for (int i = tid; i < 512; i += 256) {
            int r = i >> 2;
            int c = (i & 3) << 2;
            float4 av = *reinterpret_cast<const float4*>(
                &QP[(size_t)(row0 + r) * DD + k0 + c]);
            As[c + 0][r] = av.x; As[c + 1][r] = av.y;
            As[c + 2][r] = av.z; As[c + 3][r] = av.w;
        }
        #pragma unroll
        for (int i = tid; i < 512; i += 256) {
            int r = i >> 2;
            int c = (i & 3) << 2;
            float4 bv = *reinterpret_cast<const float4*>(
                &Bb[(size_t)(col0 + r) * DD + k0 + c]);
            Bs[c + 0][r] = bv.x; Bs[c + 1][r] = bv.y;
            Bs[c + 2][r] = bv.z; Bs[c + 3][r] = bv.w;
        }
        __syncthreads();
        #pragma unroll
        for (int kk = 0; kk < 16; ++kk) {
            float a[8], bf[8];
            #pragma unroll
            for (int i = 0; i < 8; ++i) a[i] = As[kk][ty * 8 + i];
            #pragma unroll
            for (int j = 0; j < 8; ++j) bf[j] = Bs[kk][tx * 8 + j];
            #pragma unroll
            for (int i = 0; i < 8; ++i)
                #pragma unroll
                for (int j = 0; j < 8; ++j)
                    acc[i][j] = fmaf(a[i], bf[j], acc[i][j]);
        }
        __syncthreads();
    }
    #pragma unroll
    for (int i = 0; i < 8; ++i) {
        int r = row0 + ty * 8 + i;
        float qq = q2[r];
        float tmp[8];
        #pragma unroll
        for (int j = 0; j < 8; ++j) {
            int cc = col0 + tx * 8 + j;
            float sq = qq + k2b[cc] - 2.f * acc[i][j];
            tmp[j] = -sqrtf(fmaxf(sq, 0.f));
        }
        float* orow = &Kb[(size_t)r * NP + col0 + tx * 8];
        *reinterpret_cast<float4*>(orow)     = make_float4(tmp[0], tmp[1], tmp[2], tmp[3]);
        *reinterpret_cast<float4*>(orow + 4) = make_float4(tmp[4], tmp[5], tmp[6], tmp[7]);
    }
}

// ---------------------------------------------------------------------------
// u update: u[b,n] = LOG_A - LSE_t( Kmat[b,t,n] + v[b,t] )
// Block = 256 threads = 64 columns x 4 T-phases (keeps exp chain short).
// Grid: (NP/64, BB).
// ---------------------------------------------------------------------------
__global__ __launch_bounds__(256) void u_update(
    const float* __restrict__ Kmat, const float* __restrict__ vv,
    float* __restrict__ uu)
{
    const int b = blockIdx.y;
    const int c = threadIdx.x & 63;
    const int p = threadIdx.x >> 6;
    const int n = blockIdx.x * 64 + c;
    const float* Kb = Kmat + (size_t)b * TT * NP + n;
    const float* vb = vv + (size_t)b * TT;

    float m = -INFINITY, s = 0.f;
    const int t0 = p * (TT / 4);
    for (int tt = 0; tt < TT / 4; ++tt) {
        int t = t0 + tt;
        float x = Kb[(size_t)t * NP] + vb[t];
        float nm = fmaxf(m, x);
        s = s * __expf(m - nm) + __expf(x - nm);
        m = nm;
    }
    __shared__ float sm[4][64], ss[4][64];
    sm[p][c] = m; ss[p][c] = s;
    __syncthreads();
    if (p == 0) {
        #pragma unroll
        for (int q = 1; q < 4; ++q) {
            float m2 = sm[q][c], s2 = ss[q][c];
            float nm = fmaxf(m, m2);
            s = s * __expf(m - nm) + s2 * __expf(m2 - nm);
            m = nm;
        }
        uu[(size_t)b * NP + n] = LOG_A - (m + __logf(s));
    }
}

// ---------------------------------------------------------------------------
// v update: v[b,t] = -LSE_n( Kmat[b,t,n] + u[b,n] )   (log_b = 0)
// One block (256 threads) per row.
// ---------------------------------------------------------------------------
__global__ __launch_bounds__(256) void v_update(
    const float* __restrict__ Kmat, const float* __restrict__ uu,
    float* __restrict__ vv)
{
    const int b = blockIdx.y;
    const int t = blockIdx.x;
    const float* Kb = Kmat + ((size_t)b * TT + t) * NP;
    const float* ub = uu + (size_t)b * NP;
    const int tid = threadIdx.x;

    float m = -INFINITY, s = 0.f;
    #pragma unroll
    for (int n = tid; n < NP; n += 256) {
        float x = Kb[n] + ub[n];
        float nm = fmaxf(m, x);
        s = s * __expf(m - nm) + __expf(x - nm);
        m = nm;
    }
    __shared__ float sm[256], ss[256];
    sm[tid] = m; ss[tid] = s;
    __syncthreads();
    for (int off = 128; off; off >>= 1) {
        if (tid < off) {
            float m1 = sm[tid], s1 = ss[tid];
            float m2 = sm[tid + off], s2 = ss[tid + off];
            float nm = fmaxf(m1, m2);
            ss[tid] = s1 * __expf(m1 - nm) + s2 * __expf(m2 - nm);
            sm[tid] = nm;
        }
        __syncthreads();
    }
    if (tid == 0) vv[(size_t)b * TT + t] = -(sm[0] + __logf(ss[0]));
}

// ---------------------------------------------------------------------------
// Fused pi @ vp:  out[b,t,d] = sum_n exp(Kmat[b,t,n]+u[b,n]+v[b,t]) * vp[b,n,d]
// NN GEMM, M=TT, N=DD, K=NP; exp applied on A-tile load.
// ---------------------------------------------------------------------------
__global__ __launch_bounds__(256) void gemm_pi(
    const float* __restrict__ Kmat, const float* __restrict__ uu,
    const float* __restrict__ vv, const float* __restrict__ VP,
    float* __restrict__ out)
{
    const int b = blockIdx.z;
    const float* Kb = Kmat + (size_t)b * TT * NP;
    const float* ub = uu + (size_t)b * NP;
    const float* vb = vv + (size_t)b * TT;
    const float* Bb = VP + (size_t)b * NP * DD;
    float* Ob = out + (size_t)b * TT * DD;

    __shared__ float As[16][132];
    __shared__ float Bs[16][132];
    const int tid = threadIdx.x;
    const int tx = tid & 15;
    const int ty = tid >> 4;
    const int row0 = blockIdx.y * 128;   // t tile
    const int col0 = blockIdx.x * 128;   // d tile
    float acc[8][8] = {};

    for (int k0 = 0; k0 < NP; k0 += 16) {
        #pragma unroll
        for (int i = tid; i < 512; i += 256) {
            int r = i >> 2;
            int c = (i & 3) << 2;
            float4 av = *reinterpret_cast<const float4*>(
                &Kb[(size_t)(row0 + r) * NP + k0 + c]);
            float4 uv = *reinterpret_cast<const float4*>(&ub[k0 + c]);
            float vr = vb[row0 + r];
            As[c + 0][r] = __expf(av.x + uv.x + vr);
            As[c + 1][r] = __expf(av.y + uv.y + vr);
            As[c + 2][r] = __expf(av.z + uv.z + vr);
            As[c + 3][r] = __expf(av.w + uv.w + vr);
        }
        #pragma unroll
        for (int i = tid; i < 512; i += 256) {
            int r = i >> 5;
            int c = (i & 31) << 2;
            *reinterpret_cast<float4*>(&Bs[r][c]) =
                *reinterpret_cast<const float4*>(&Bb[(size_t)(k0 + r) * DD + col0 + c]);
        }
        __syncthreads();
        #pragma unroll
        for (int kk = 0; kk < 16; ++kk) {
            float a[8], bf[8];
            #pragma unroll
            for (int i = 0; i < 8; ++i) a[i] = As[kk][ty * 8 + i];
            #pragma unroll
            for (int j = 0; j < 8; ++j) bf[j] = Bs[kk][tx * 8 + j];
            #pragma unroll
            for (int i = 0; i < 8; ++i)
                #pragma unroll
                for (int j = 0; j < 8; ++j)
                    acc[i][j] = fmaf(a[i], bf[j], acc[i][j]);
        }
        __syncthreads();
    }
    #pragma unroll
    for (int i = 0; i < 8; ++i) {
        float* crow = &Ob[(size_t)(row0 + ty * 8 + i) * DD + col0 + tx * 8];
        *reinterpret_cast<float4*>(crow) =
            make_float4(acc[i][0], acc[i][1], acc[i][2], acc[i][3]);
        *reinterpret_cast<float4*>(crow + 4) =
            make_float4(acc[i][4], acc[i][5], acc[i][6], acc[i][7]);
    }
}

// ---------------------------------------------------------------------------
extern "C" void kernel_launch(void* const* d_in, const int* in_sizes, int n_in,
                              void* d_out, int out_size, void* d_ws, size_t ws_size,
                              hipStream_t stream)
{
    const float* q  = (const float*)d_in[0];
    const float* k  = (const float*)d_in[1];
    const float* v  = (const float*)d_in[2];
    const float* Qw = (const float*)d_in[3];
    const float* Kw = (const float*)d_in[4];
    const float* Vw = (const float*)d_in[5];
    float* out = (float*)d_out;

    // Workspace layout (~196.2 MiB total)
    char* p = (char*)d_ws;
    float* qp = (float*)p; p += (size_t)TT * DD * 4;        //   4 MiB
    float* kp = (float*)p; p += (size_t)BB * NP * DD * 4;   //  32 MiB
    float* vp = (float*)p; p += (size_t)BB * NP * DD * 4;   //  32 MiB
    float* q2 = (float*)p; p += (size_t)TT * 4;
    float* k2 = (float*)p; p += (size_t)BB * NP * 4;
    float* uu = (float*)p; p += (size_t)BB * NP * 4;
    float* vv = (float*)p; p += (size_t)BB * TT * 4;
    float* Km = (float*)p;                                   // 128 MiB

    dim3 blk(256);

    // Projections
    gemm_nn<<<dim3(DD / 128, TT / 128), blk, 0, stream>>>(q, Qw, qp, TT, DD, DD);
    gemm_nn<<<dim3(DD / 128, (BB * NP) / 128), blk, 0, stream>>>(k, Kw, kp, BB * NP, DD, DD);
    gemm_nn<<<dim3(DD / 128, (BB * NP) / 128), blk, 0, stream>>>(v, Vw, vp, BB * NP, DD, DD);

    // Squared norms
    rownorm<<<dim3(TT / 4), blk, 0, stream>>>(qp, q2, TT);
    rownorm<<<dim3((BB * NP) / 4), blk, 0, stream>>>(kp, k2, BB * NP);

    // Cost matrix -> Kmat
    gemm_nt_cost<<<dim3(NP / 128, TT / 128, BB), blk, 0, stream>>>(qp, kp, q2, k2, Km);

    // Sinkhorn iterations (v starts at 0)
    hipMemsetAsync(vv, 0, (size_t)BB * TT * 4, stream);
    for (int it = 0; it < 5; ++it) {
        u_update<<<dim3(NP / 64, BB), blk, 0, stream>>>(Km, vv, uu);
        v_update<<<dim3(TT, BB), blk, 0, stream>>>(Km, uu, vv);
    }

    // out = exp(Kmat+u+v) @ vp (fused)
    gemm_pi<<<dim3(DD / 128, TT / 128, BB), blk, 0, stream>>>(Km, uu, vv, vp, out);
}